// Round 1
// baseline (495.761 us; speedup 1.0000x reference)
//
#include <hip/hip_runtime.h>

#define HW 4096
#define BN_RS 0.9999950000374998f   // 1/sqrt(1+1e-5)

__device__ __forceinline__ float silu_f(float v) { return v / (1.0f + __expf(-v)); }
__device__ __forceinline__ int clamp64(int v) { return v < 0 ? 0 : (v > 63 ? 63 : v); }

// ---------------- 1x1 conv + BN + SiLU as tiled GEMM ----------------
// Y[b][co][p] = silu( (sum_ci Wt[co][ci] * X[b][ci][p]) * g[co]*BN_RS + bb[co] )
template<int CO, int CIN>
__global__ __launch_bounds__(256) void k_conv1x1_bn_silu(
    const float* __restrict__ X, const float* __restrict__ Wt,
    const float* __restrict__ gg, const float* __restrict__ bb,
    float* __restrict__ Y)
{
    const int b  = blockIdx.z;
    const int p0 = blockIdx.x * 64;
    const int c0 = blockIdx.y * 64;
    const int tid = threadIdx.x;
    const int tx = tid & 15, ty = tid >> 4;

    __shared__ float As[32][68];   // [k][co], padded
    __shared__ float Bs[32][64];   // [k][p]

    const float* Xb = X + (size_t)b * CIN * HW;
    float acc[4][4] = {};

    for (int k0 = 0; k0 < CIN; k0 += 32) {
        // A tile: 64 co rows x 32 k
        #pragma unroll
        for (int it = 0; it < 2; ++it) {
            int i   = tid + it * 256;
            int row = i >> 3;
            int kc  = (i & 7) << 2;
            float4 v = *(const float4*)&Wt[(size_t)(c0 + row) * CIN + (k0 + kc)];
            As[kc + 0][row] = v.x; As[kc + 1][row] = v.y;
            As[kc + 2][row] = v.z; As[kc + 3][row] = v.w;
        }
        // B tile: 32 k rows x 64 p
        #pragma unroll
        for (int it = 0; it < 2; ++it) {
            int i   = tid + it * 256;
            int row = i >> 4;
            int c4  = (i & 15) << 2;
            *(float4*)&Bs[row][c4] = *(const float4*)&Xb[(size_t)(k0 + row) * HW + p0 + c4];
        }
        __syncthreads();
        #pragma unroll
        for (int k = 0; k < 32; ++k) {
            const float4 av = *(const float4*)&As[k][ty << 2];
            const float4 bv = *(const float4*)&Bs[k][tx << 2];
            const float a0 = av.x, a1 = av.y, a2 = av.z, a3 = av.w;
            const float b0 = bv.x, b1 = bv.y, b2 = bv.z, b3 = bv.w;
            acc[0][0] = fmaf(a0, b0, acc[0][0]); acc[0][1] = fmaf(a0, b1, acc[0][1]);
            acc[0][2] = fmaf(a0, b2, acc[0][2]); acc[0][3] = fmaf(a0, b3, acc[0][3]);
            acc[1][0] = fmaf(a1, b0, acc[1][0]); acc[1][1] = fmaf(a1, b1, acc[1][1]);
            acc[1][2] = fmaf(a1, b2, acc[1][2]); acc[1][3] = fmaf(a1, b3, acc[1][3]);
            acc[2][0] = fmaf(a2, b0, acc[2][0]); acc[2][1] = fmaf(a2, b1, acc[2][1]);
            acc[2][2] = fmaf(a2, b2, acc[2][2]); acc[2][3] = fmaf(a2, b3, acc[2][3]);
            acc[3][0] = fmaf(a3, b0, acc[3][0]); acc[3][1] = fmaf(a3, b1, acc[3][1]);
            acc[3][2] = fmaf(a3, b2, acc[3][2]); acc[3][3] = fmaf(a3, b3, acc[3][3]);
        }
        __syncthreads();
    }
    #pragma unroll
    for (int i = 0; i < 4; ++i) {
        int co = c0 + (ty << 2) + i;
        float s  = gg[co] * BN_RS;
        float bi = bb[co];
        float4 o;
        o.x = silu_f(fmaf(acc[i][0], s, bi));
        o.y = silu_f(fmaf(acc[i][1], s, bi));
        o.z = silu_f(fmaf(acc[i][2], s, bi));
        o.w = silu_f(fmaf(acc[i][3], s, bi));
        *(float4*)&Y[((size_t)b * CO + co) * HW + p0 + (tx << 2)] = o;
    }
}

// ---------------- 3x3 conv (256 -> 18), pad 1, + bias ----------------
__global__ __launch_bounds__(256) void k_conv_off(
    const float* __restrict__ Hh, const float* __restrict__ Wo,
    const float* __restrict__ Bo, float* __restrict__ Off)
{
    const int y = blockIdx.x;
    const int b = blockIdx.y;
    const int tid = threadIdx.x;
    const int x = tid & 63;
    const int g = tid >> 6;

    __shared__ float hs[3][32][64];
    float acc[5] = {0.f, 0.f, 0.f, 0.f, 0.f};
    const float* Hb = Hh + (size_t)b * 256 * HW;

    for (int cc = 0; cc < 8; ++cc) {
        __syncthreads();
        #pragma unroll
        for (int it = 0; it < 6; ++it) {
            int i   = tid + it * 256;   // 0..1535
            int r   = i >> 9;
            int rem = i & 511;
            int ci  = rem >> 4;
            int x4  = (rem & 15) << 2;
            int yy  = y + r - 1;
            float4 v = make_float4(0.f, 0.f, 0.f, 0.f);
            if (yy >= 0 && yy < 64)
                v = *(const float4*)&Hb[(size_t)(cc * 32 + ci) * HW + yy * 64 + x4];
            *(float4*)&hs[r][ci][x4] = v;
        }
        __syncthreads();
        for (int ci = 0; ci < 32; ++ci) {
            float v[9];
            #pragma unroll
            for (int r = 0; r < 3; ++r) {
                v[r * 3 + 0] = (x > 0)  ? hs[r][ci][x - 1] : 0.0f;
                v[r * 3 + 1] = hs[r][ci][x];
                v[r * 3 + 2] = (x < 63) ? hs[r][ci][x + 1] : 0.0f;
            }
            int cig = cc * 32 + ci;
            #pragma unroll
            for (int j = 0; j < 5; ++j) {
                int co = g + (j << 2);
                if (co < 18) {
                    const float* w = &Wo[((size_t)co * 256 + cig) * 9];
                    float a = acc[j];
                    #pragma unroll
                    for (int t9 = 0; t9 < 9; ++t9) a = fmaf(w[t9], v[t9], a);
                    acc[j] = a;
                }
            }
        }
    }
    #pragma unroll
    for (int j = 0; j < 5; ++j) {
        int co = g + (j << 2);
        if (co < 18)
            Off[((size_t)b * 18 + co) * HW + y * 64 + x] = acc[j] + Bo[co];
    }
}

// ------------- deformable depthwise 3x3 + BN + SiLU + residual -------------
__global__ __launch_bounds__(256) void k_deform(
    const float* __restrict__ Hh, const float* __restrict__ Off,
    const float* __restrict__ Wd, const float* __restrict__ Gb,
    const float* __restrict__ Bb, float* __restrict__ H2)
{
    const int y = blockIdx.x;
    const int b = blockIdx.y;
    const int tid = threadIdx.x;
    const int x = tid & 63;
    const int g = tid >> 6;

    int   i00[9], i01[9], i10[9], i11[9];
    float w00[9], w01[9], w10[9], w11[9];

    const float* Ob = Off + (size_t)b * 18 * HW + y * 64 + x;
    #pragma unroll
    for (int k = 0; k < 9; ++k) {
        float dy = Ob[(size_t)(2 * k) * HW];
        float dx = Ob[(size_t)(2 * k + 1) * HW];
        float py = (float)(y + k / 3 - 1) + dy;
        float px = (float)(x + k % 3 - 1) + dx;
        float fy0 = floorf(py), fx0 = floorf(px);
        int y0 = (int)fy0, x0 = (int)fx0;
        float fy = py - fy0, fx = px - fx0;
        int y1 = y0 + 1, x1 = x0 + 1;
        float gy0 = 1.0f - fy, gx0 = 1.0f - fx;
        bool vy0 = ((unsigned)y0 < 64u), vy1 = ((unsigned)y1 < 64u);
        bool vx0 = ((unsigned)x0 < 64u), vx1 = ((unsigned)x1 < 64u);
        int cy0 = clamp64(y0), cy1 = clamp64(y1);
        int cx0 = clamp64(x0), cx1 = clamp64(x1);
        i00[k] = cy0 * 64 + cx0; i01[k] = cy0 * 64 + cx1;
        i10[k] = cy1 * 64 + cx0; i11[k] = cy1 * 64 + cx1;
        w00[k] = (vy0 && vx0) ? gy0 * gx0 : 0.0f;
        w01[k] = (vy0 && vx1) ? gy0 * fx  : 0.0f;
        w10[k] = (vy1 && vx0) ? fy  * gx0 : 0.0f;
        w11[k] = (vy1 && vx1) ? fy  * fx  : 0.0f;
    }

    for (int c = g; c < 256; c += 4) {
        const float* hb = Hh + ((size_t)(b * 256 + c) << 12);
        const float* wd = Wd + c * 9;
        float acc = 0.0f;
        #pragma unroll
        for (int k = 0; k < 9; ++k) {
            float val = hb[i00[k]] * w00[k] + hb[i01[k]] * w01[k]
                      + hb[i10[k]] * w10[k] + hb[i11[k]] * w11[k];
            acc = fmaf(val, wd[k], acc);
        }
        float t = fmaf(acc, Gb[c] * BN_RS, Bb[c]);
        H2[((size_t)(b * 256 + c) << 12) + y * 64 + x] = silu_f(t) + hb[y * 64 + x];
    }
}

// ---------------- SE: global mean over HxW ----------------
__global__ __launch_bounds__(256) void k_se_reduce(
    const float* __restrict__ Y, float* __restrict__ sb)
{
    const int bc = blockIdx.x;   // b*512+co
    const float4* p = (const float4*)(Y + (size_t)bc * HW);
    int tid = threadIdx.x;
    float s = 0.f;
    #pragma unroll
    for (int it = 0; it < 4; ++it) {
        float4 v = p[tid + it * 256];
        s += v.x + v.y + v.z + v.w;
    }
    #pragma unroll
    for (int o = 32; o > 0; o >>= 1) s += __shfl_down(s, o);
    __shared__ float red[4];
    if ((tid & 63) == 0) red[tid >> 6] = s;
    __syncthreads();
    if (tid == 0) sb[bc] = (red[0] + red[1] + red[2] + red[3]) * (1.0f / 4096.0f);
}

// ---------------- SE: fc1(silu) + fc2(sigmoid) ----------------
__global__ __launch_bounds__(256) void k_se_fc(
    const float* __restrict__ sb, const float* __restrict__ wf1,
    const float* __restrict__ bf1, const float* __restrict__ wf2,
    const float* __restrict__ bf2, float* __restrict__ s2)
{
    const int b = blockIdx.x;
    const int t = threadIdx.x;
    __shared__ float sv[512];
    __shared__ float s1[32];
    sv[t]       = sb[b * 512 + t];
    sv[t + 256] = sb[b * 512 + t + 256];
    __syncthreads();
    if (t < 32) {
        float a = bf1[t];
        const float* w = wf1 + t * 512;
        for (int i = 0; i < 512; ++i) a = fmaf(w[i], sv[i], a);
        s1[t] = silu_f(a);
    }
    __syncthreads();
    #pragma unroll
    for (int it = 0; it < 2; ++it) {
        int co = t + it * 256;
        float a = bf2[co];
        const float* w = wf2 + co * 32;
        #pragma unroll
        for (int i = 0; i < 32; ++i) a = fmaf(w[i], s1[i], a);
        s2[b * 512 + co] = 1.0f / (1.0f + __expf(-a));
    }
}

// ---------------- final: out *= s ----------------
__global__ __launch_bounds__(256) void k_se_scale(
    float* __restrict__ Y, const float* __restrict__ s2)
{
    size_t i = (size_t)blockIdx.x * 256 + threadIdx.x;  // float4 index, 2,097,152 total
    int bc = (int)(i >> 10);                            // 1024 float4 per plane
    float sc = s2[bc];
    float4 v = ((float4*)Y)[i];
    v.x *= sc; v.y *= sc; v.z *= sc; v.w *= sc;
    ((float4*)Y)[i] = v;
}

extern "C" void kernel_launch(void* const* d_in, const int* in_sizes, int n_in,
                              void* d_out, int out_size, void* d_ws, size_t ws_size,
                              hipStream_t stream)
{
    const float* x   = (const float*)d_in[0];
    const float* w1  = (const float*)d_in[1];
    const float* g1  = (const float*)d_in[2];
    const float* b1  = (const float*)d_in[3];
    const float* wof = (const float*)d_in[4];
    const float* bof = (const float*)d_in[5];
    const float* wdw = (const float*)d_in[6];
    const float* gb  = (const float*)d_in[7];
    const float* bbv = (const float*)d_in[8];
    const float* w2  = (const float*)d_in[9];
    const float* g2  = (const float*)d_in[10];
    const float* b2  = (const float*)d_in[11];
    const float* wf1 = (const float*)d_in[12];
    const float* bf1 = (const float*)d_in[13];
    const float* wf2 = (const float*)d_in[14];
    const float* bf2 = (const float*)d_in[15];
    float* out = (float*)d_out;

    const size_t n_h   = 4ull * 256 * HW;   // 4,194,304
    const size_t n_off = 4ull * 18 * HW;    //   294,912
    float* ws = (float*)d_ws;
    float *h, *offb, *h2, *sb, *s2;
    size_t need = (2 * n_h + n_off + 4096) * sizeof(float);
    if (ws_size >= need) {
        h = ws; offb = h + n_h; h2 = offb + n_off; sb = h2 + n_h; s2 = sb + 2048;
    } else {
        // fall back: use d_out as scratch for h (dead before y is written)
        h = out; offb = ws; h2 = offb + n_off; sb = h2 + n_h; s2 = sb + 2048;
    }

    k_conv1x1_bn_silu<256, 512><<<dim3(64, 4, 4), 256, 0, stream>>>(x, w1, g1, b1, h);
    k_conv_off<<<dim3(64, 4), 256, 0, stream>>>(h, wof, bof, offb);
    k_deform<<<dim3(64, 4), 256, 0, stream>>>(h, offb, wdw, gb, bbv, h2);
    k_conv1x1_bn_silu<512, 256><<<dim3(64, 8, 4), 256, 0, stream>>>(h2, w2, g2, b2, out);
    k_se_reduce<<<2048, 256, 0, stream>>>(out, sb);
    k_se_fc<<<4, 256, 0, stream>>>(sb, wf1, bf1, wf2, bf2, s2);
    k_se_scale<<<8192, 256, 0, stream>>>(out, s2);
}

// Round 2
// 334.360 us; speedup vs baseline: 1.4827x; 1.4827x over previous
//
#include <hip/hip_runtime.h>

#define HW 4096
#define BN_RS 0.9999950000374998f   // 1/sqrt(1+1e-5)

__device__ __forceinline__ float silu_f(float v) { return v / (1.0f + __expf(-v)); }
__device__ __forceinline__ int clamp64(int v) { return v < 0 ? 0 : (v > 63 ? 63 : v); }

// ---------------- 1x1 conv + BN + SiLU as tiled GEMM ----------------
template<int CO, int CIN>
__global__ __launch_bounds__(256) void k_conv1x1_bn_silu(
    const float* __restrict__ X, const float* __restrict__ Wt,
    const float* __restrict__ gg, const float* __restrict__ bb,
    float* __restrict__ Y)
{
    const int b  = blockIdx.z;
    const int p0 = blockIdx.x * 64;
    const int c0 = blockIdx.y * 64;
    const int tid = threadIdx.x;
    const int tx = tid & 15, ty = tid >> 4;

    __shared__ float As[32][68];   // [k][co], padded
    __shared__ float Bs[32][64];   // [k][p]

    const float* Xb = X + (size_t)b * CIN * HW;
    float acc[4][4] = {};

    for (int k0 = 0; k0 < CIN; k0 += 32) {
        #pragma unroll
        for (int it = 0; it < 2; ++it) {
            int i   = tid + it * 256;
            int row = i >> 3;
            int kc  = (i & 7) << 2;
            float4 v = *(const float4*)&Wt[(size_t)(c0 + row) * CIN + (k0 + kc)];
            As[kc + 0][row] = v.x; As[kc + 1][row] = v.y;
            As[kc + 2][row] = v.z; As[kc + 3][row] = v.w;
        }
        #pragma unroll
        for (int it = 0; it < 2; ++it) {
            int i   = tid + it * 256;
            int row = i >> 4;
            int c4  = (i & 15) << 2;
            *(float4*)&Bs[row][c4] = *(const float4*)&Xb[(size_t)(k0 + row) * HW + p0 + c4];
        }
        __syncthreads();
        #pragma unroll
        for (int k = 0; k < 32; ++k) {
            const float4 av = *(const float4*)&As[k][ty << 2];
            const float4 bv = *(const float4*)&Bs[k][tx << 2];
            const float a0 = av.x, a1 = av.y, a2 = av.z, a3 = av.w;
            const float b0 = bv.x, b1 = bv.y, b2 = bv.z, b3 = bv.w;
            acc[0][0] = fmaf(a0, b0, acc[0][0]); acc[0][1] = fmaf(a0, b1, acc[0][1]);
            acc[0][2] = fmaf(a0, b2, acc[0][2]); acc[0][3] = fmaf(a0, b3, acc[0][3]);
            acc[1][0] = fmaf(a1, b0, acc[1][0]); acc[1][1] = fmaf(a1, b1, acc[1][1]);
            acc[1][2] = fmaf(a1, b2, acc[1][2]); acc[1][3] = fmaf(a1, b3, acc[1][3]);
            acc[2][0] = fmaf(a2, b0, acc[2][0]); acc[2][1] = fmaf(a2, b1, acc[2][1]);
            acc[2][2] = fmaf(a2, b2, acc[2][2]); acc[2][3] = fmaf(a2, b3, acc[2][3]);
            acc[3][0] = fmaf(a3, b0, acc[3][0]); acc[3][1] = fmaf(a3, b1, acc[3][1]);
            acc[3][2] = fmaf(a3, b2, acc[3][2]); acc[3][3] = fmaf(a3, b3, acc[3][3]);
        }
        __syncthreads();
    }
    #pragma unroll
    for (int i = 0; i < 4; ++i) {
        int co = c0 + (ty << 2) + i;
        float s  = gg[co] * BN_RS;
        float bi = bb[co];
        float4 o;
        o.x = silu_f(fmaf(acc[i][0], s, bi));
        o.y = silu_f(fmaf(acc[i][1], s, bi));
        o.z = silu_f(fmaf(acc[i][2], s, bi));
        o.w = silu_f(fmaf(acc[i][3], s, bi));
        *(float4*)&Y[((size_t)b * CO + co) * HW + p0 + (tx << 2)] = o;
    }
}

// -------- 3x3 conv (256 -> 18), pad 1, channel-split partial sums --------
// grid (y=64, b=4, q=4); block 256 = 64 x * 4 g; each block: 64 input ch.
// OffP[q][b][co][HW] partial (no bias).
__global__ __launch_bounds__(256) void k_conv_off(
    const float* __restrict__ Hh, const float* __restrict__ Wo,
    float* __restrict__ OffP)
{
    const int y = blockIdx.x;
    const int b = blockIdx.y;
    const int q = blockIdx.z;
    const int tid = threadIdx.x;
    const int x = tid & 63;
    const int g = tid >> 6;

    __shared__ __align__(16) float hs[3][32][66];   // x-padded halo
    __shared__ __align__(16) float ws[18][32][12];  // taps padded to 12 for b128

    if (tid < 96) {                   // zero the x halo once
        int r = tid >> 5, ci = tid & 31;
        hs[r][ci][0] = 0.f; hs[r][ci][65] = 0.f;
    }

    float acc[5] = {0.f, 0.f, 0.f, 0.f, 0.f};
    const float* Hb = Hh + (size_t)b * 256 * HW;

    for (int cc = 0; cc < 2; ++cc) {
        const int c0 = q * 64 + cc * 32;
        __syncthreads();
        // stage weights: Wo[co][c0+ci][t] -> ws[co][ci][t]
        for (int i = tid; i < 5184; i += 256) {
            int co = i / 288, r = i % 288;
            int ci = r / 9, t = r - ci * 9;
            ws[co][ci][t] = Wo[(size_t)co * 2304 + (size_t)(c0 + ci) * 9 + t];
        }
        // stage h rows y-1..y+1 for 32 channels
        #pragma unroll
        for (int it = 0; it < 6; ++it) {
            int i   = tid + it * 256;   // float4 units, 0..1535
            int r   = i >> 9;
            int rem = i & 511;
            int ci  = rem >> 4;
            int x4  = (rem & 15) << 2;
            int yy  = y + r - 1;
            float4 v = make_float4(0.f, 0.f, 0.f, 0.f);
            if ((unsigned)yy < 64u)
                v = *(const float4*)&Hb[(size_t)(c0 + ci) * HW + yy * 64 + x4];
            hs[r][ci][1 + x4] = v.x;
            hs[r][ci][2 + x4] = v.y;
            hs[r][ci][3 + x4] = v.z;
            hs[r][ci][4 + x4] = v.w;
        }
        __syncthreads();
        #pragma unroll 2
        for (int ci = 0; ci < 32; ++ci) {
            float v[9];
            #pragma unroll
            for (int r = 0; r < 3; ++r) {
                v[r * 3 + 0] = hs[r][ci][x];
                v[r * 3 + 1] = hs[r][ci][x + 1];
                v[r * 3 + 2] = hs[r][ci][x + 2];
            }
            #pragma unroll
            for (int j = 0; j < 5; ++j) {
                int co = g + (j << 2);
                if (co < 18) {
                    const float4 w0 = *(const float4*)&ws[co][ci][0];
                    const float4 w1 = *(const float4*)&ws[co][ci][4];
                    const float  w8 = ws[co][ci][8];
                    float a = acc[j];
                    a = fmaf(w0.x, v[0], a); a = fmaf(w0.y, v[1], a);
                    a = fmaf(w0.z, v[2], a); a = fmaf(w0.w, v[3], a);
                    a = fmaf(w1.x, v[4], a); a = fmaf(w1.y, v[5], a);
                    a = fmaf(w1.z, v[6], a); a = fmaf(w1.w, v[7], a);
                    a = fmaf(w8,   v[8], a);
                    acc[j] = a;
                }
            }
        }
    }
    #pragma unroll
    for (int j = 0; j < 5; ++j) {
        int co = g + (j << 2);
        if (co < 18)
            OffP[(((size_t)q * 4 + b) * 18 + co) * HW + y * 64 + x] = acc[j];
    }
}

// ------------- deformable depthwise 3x3 + BN + SiLU + residual -------------
__global__ __launch_bounds__(256) void k_deform(
    const float* __restrict__ Hh, const float* __restrict__ OffP,
    const float* __restrict__ Bo, const float* __restrict__ Wd,
    const float* __restrict__ Gb, const float* __restrict__ Bb,
    float* __restrict__ H2)
{
    const int y = blockIdx.x;
    const int b = blockIdx.y;
    const int tid = threadIdx.x;
    const int x = tid & 63;
    const int g = tid >> 6;
    const int pos = y * 64 + x;

    int   i00[9], i01[9], i10[9], i11[9];
    float w00[9], w01[9], w10[9], w11[9];

    #pragma unroll
    for (int k = 0; k < 9; ++k) {
        float dy = Bo[2 * k], dx = Bo[2 * k + 1];
        #pragma unroll
        for (int s = 0; s < 4; ++s) {
            const float* P = OffP + (((size_t)s * 4 + b) * 18) * HW + pos;
            dy += P[(size_t)(2 * k) * HW];
            dx += P[(size_t)(2 * k + 1) * HW];
        }
        float py = (float)(y + k / 3 - 1) + dy;
        float px = (float)(x + k % 3 - 1) + dx;
        float fy0 = floorf(py), fx0 = floorf(px);
        int y0 = (int)fy0, x0 = (int)fx0;
        float fy = py - fy0, fx = px - fx0;
        int y1 = y0 + 1, x1 = x0 + 1;
        float gy0 = 1.0f - fy, gx0 = 1.0f - fx;
        bool vy0 = ((unsigned)y0 < 64u), vy1 = ((unsigned)y1 < 64u);
        bool vx0 = ((unsigned)x0 < 64u), vx1 = ((unsigned)x1 < 64u);
        int cy0 = clamp64(y0), cy1 = clamp64(y1);
        int cx0 = clamp64(x0), cx1 = clamp64(x1);
        i00[k] = cy0 * 64 + cx0; i01[k] = cy0 * 64 + cx1;
        i10[k] = cy1 * 64 + cx0; i11[k] = cy1 * 64 + cx1;
        w00[k] = (vy0 && vx0) ? gy0 * gx0 : 0.0f;
        w01[k] = (vy0 && vx1) ? gy0 * fx  : 0.0f;
        w10[k] = (vy1 && vx0) ? fy  * gx0 : 0.0f;
        w11[k] = (vy1 && vx1) ? fy  * fx  : 0.0f;
    }

    for (int c = g; c < 256; c += 4) {
        const float* hb = Hh + ((size_t)(b * 256 + c) << 12);
        const float* wd = Wd + c * 9;
        float acc = 0.0f;
        #pragma unroll
        for (int k = 0; k < 9; ++k) {
            float val = hb[i00[k]] * w00[k] + hb[i01[k]] * w01[k]
                      + hb[i10[k]] * w10[k] + hb[i11[k]] * w11[k];
            acc = fmaf(val, wd[k], acc);
        }
        float t = fmaf(acc, Gb[c] * BN_RS, Bb[c]);
        H2[((size_t)(b * 256 + c) << 12) + pos] = silu_f(t) + hb[pos];
    }
}

// ---------------- SE: global mean over HxW ----------------
__global__ __launch_bounds__(256) void k_se_reduce(
    const float* __restrict__ Y, float* __restrict__ sb)
{
    const int bc = blockIdx.x;
    const float4* p = (const float4*)(Y + (size_t)bc * HW);
    int tid = threadIdx.x;
    float s = 0.f;
    #pragma unroll
    for (int it = 0; it < 4; ++it) {
        float4 v = p[tid + it * 256];
        s += v.x + v.y + v.z + v.w;
    }
    #pragma unroll
    for (int o = 32; o > 0; o >>= 1) s += __shfl_down(s, o);
    __shared__ float red[4];
    if ((tid & 63) == 0) red[tid >> 6] = s;
    __syncthreads();
    if (tid == 0) sb[bc] = (red[0] + red[1] + red[2] + red[3]) * (1.0f / 4096.0f);
}

// ---------------- SE: fc1(silu) + fc2(sigmoid) ----------------
__global__ __launch_bounds__(256) void k_se_fc(
    const float* __restrict__ sb, const float* __restrict__ wf1,
    const float* __restrict__ bf1, const float* __restrict__ wf2,
    const float* __restrict__ bf2, float* __restrict__ s2)
{
    const int b = blockIdx.x;
    const int t = threadIdx.x;
    __shared__ float sv[512];
    __shared__ float s1[32];
    sv[t]       = sb[b * 512 + t];
    sv[t + 256] = sb[b * 512 + t + 256];
    __syncthreads();
    if (t < 32) {
        float a = bf1[t];
        const float* w = wf1 + t * 512;
        for (int i = 0; i < 512; ++i) a = fmaf(w[i], sv[i], a);
        s1[t] = silu_f(a);
    }
    __syncthreads();
    #pragma unroll
    for (int it = 0; it < 2; ++it) {
        int co = t + it * 256;
        float a = bf2[co];
        const float* w = wf2 + co * 32;
        #pragma unroll
        for (int i = 0; i < 32; ++i) a = fmaf(w[i], s1[i], a);
        s2[b * 512 + co] = 1.0f / (1.0f + __expf(-a));
    }
}

// ---------------- final: out *= s ----------------
__global__ __launch_bounds__(256) void k_se_scale(
    float* __restrict__ Y, const float* __restrict__ s2)
{
    size_t i = (size_t)blockIdx.x * 256 + threadIdx.x;
    int bc = (int)(i >> 10);
    float sc = s2[bc];
    float4 v = ((float4*)Y)[i];
    v.x *= sc; v.y *= sc; v.z *= sc; v.w *= sc;
    ((float4*)Y)[i] = v;
}

extern "C" void kernel_launch(void* const* d_in, const int* in_sizes, int n_in,
                              void* d_out, int out_size, void* d_ws, size_t ws_size,
                              hipStream_t stream)
{
    const float* x   = (const float*)d_in[0];
    const float* w1  = (const float*)d_in[1];
    const float* g1  = (const float*)d_in[2];
    const float* b1  = (const float*)d_in[3];
    const float* wof = (const float*)d_in[4];
    const float* bof = (const float*)d_in[5];
    const float* wdw = (const float*)d_in[6];
    const float* gb  = (const float*)d_in[7];
    const float* bbv = (const float*)d_in[8];
    const float* w2  = (const float*)d_in[9];
    const float* g2  = (const float*)d_in[10];
    const float* b2  = (const float*)d_in[11];
    const float* wf1 = (const float*)d_in[12];
    const float* bf1 = (const float*)d_in[13];
    const float* wf2 = (const float*)d_in[14];
    const float* bf2 = (const float*)d_in[15];
    float* out = (float*)d_out;

    const size_t n_h    = 4ull * 256 * HW;        // 4,194,304
    const size_t n_offp = 4ull * 4 * 18 * HW;     // 1,179,648
    float* ws = (float*)d_ws;
    float *h, *offp, *h2, *sb, *s2;
    size_t need = (2 * n_h + n_offp + 4096) * sizeof(float);
    if (ws_size >= need) {
        h = ws; offp = h + n_h; h2 = offp + n_offp; sb = h2 + n_h; s2 = sb + 2048;
    } else {
        h = out;  // dead before conv2 writes out
        offp = ws; h2 = offp + n_offp; sb = h2 + n_h; s2 = sb + 2048;
    }

    k_conv1x1_bn_silu<256, 512><<<dim3(64, 4, 4), 256, 0, stream>>>(x, w1, g1, b1, h);
    k_conv_off<<<dim3(64, 4, 4), 256, 0, stream>>>(h, wof, offp);
    k_deform<<<dim3(64, 4), 256, 0, stream>>>(h, offp, bof, wdw, gb, bbv, h2);
    k_conv1x1_bn_silu<512, 256><<<dim3(64, 8, 4), 256, 0, stream>>>(h2, w2, g2, b2, out);
    k_se_reduce<<<2048, 256, 0, stream>>>(out, sb);
    k_se_fc<<<4, 256, 0, stream>>>(sb, wf1, bf1, wf2, bf2, s2);
    k_se_scale<<<8192, 256, 0, stream>>>(out, s2);
}

// Round 3
// 242.406 us; speedup vs baseline: 2.0452x; 1.3793x over previous
//
#include <hip/hip_runtime.h>

#define HW 4096
#define BN_RS 0.9999950000374998f   // 1/sqrt(1+1e-5)

typedef __attribute__((ext_vector_type(8))) short  short8;
typedef __attribute__((ext_vector_type(8))) unsigned short ushort8;
typedef __attribute__((ext_vector_type(4))) float  f32x4;

__device__ __forceinline__ float silu_f(float v) { return v / (1.0f + __expf(-v)); }
__device__ __forceinline__ int clamp64(int v) { return v < 0 ? 0 : (v > 63 ? 63 : v); }
__device__ __forceinline__ unsigned short f2bf(float f) {
    union { float f; unsigned u; } v; v.f = f;
    unsigned r = v.u + 0x7fff + ((v.u >> 16) & 1);   // RNE
    return (unsigned short)(r >> 16);
}

// ---------------- 1x1 conv + BN + SiLU, bf16 MFMA GEMM ----------------
// Y[b][co][p] = silu( (sum_ci W[co][ci]*X[b][ci][p]) * g*BN_RS + bb )
// Block: 64co x 64pos tile, 4 waves as 2x2 of 32x32, BK=32.
template<int CO, int CIN>
__global__ __launch_bounds__(256) void k_conv1x1_mfma(
    const float* __restrict__ X, const float* __restrict__ Wt,
    const float* __restrict__ gg, const float* __restrict__ bb,
    float* __restrict__ Y)
{
    const int b  = blockIdx.z;
    const int p0 = blockIdx.x * 64;
    const int c0 = blockIdx.y * 64;
    const int tid  = threadIdx.x;
    const int wave = tid >> 6, lane = tid & 63;
    const int wm = wave >> 1, wn = wave & 1;
    const int lrow = lane & 15, lkg = lane >> 4;

    // stride 40 bf16 = 80 B: 16B-aligned rows, 2-way banks on b128 frag reads
    __shared__ __align__(16) unsigned short As[64 * 40];  // [co][k]
    __shared__ __align__(16) unsigned short Bs[64 * 40];  // [pos][k], k-group XOR swizzle

    const float* Xb = X + (size_t)b * CIN * HW;

    f32x4 acc[2][2];
    #pragma unroll
    for (int i = 0; i < 2; ++i)
        #pragma unroll
        for (int j = 0; j < 2; ++j) acc[i][j] = (f32x4){0.f, 0.f, 0.f, 0.f};

    const int arow = tid >> 2, akc = (tid & 3) * 8;

    for (int k0 = 0; k0 < CIN; k0 += 32) {
        __syncthreads();
        // stage A: W[c0+row][k0+akc..+8] -> bf16 As[row][akc..]
        {
            const float* wp = &Wt[(size_t)(c0 + arow) * CIN + k0 + akc];
            float4 v0 = *(const float4*)wp;
            float4 v1 = *(const float4*)(wp + 4);
            ushort8 u;
            u[0] = f2bf(v0.x); u[1] = f2bf(v0.y); u[2] = f2bf(v0.z); u[3] = f2bf(v0.w);
            u[4] = f2bf(v1.x); u[5] = f2bf(v1.y); u[6] = f2bf(v1.z); u[7] = f2bf(v1.w);
            *(ushort8*)&As[arow * 40 + akc] = u;
        }
        // stage B: X[k0+kk][p0+p4..+4] -> bf16 Bs[pos][k] (transposed, swizzled)
        #pragma unroll
        for (int it = 0; it < 2; ++it) {
            int i  = tid + it * 256;          // 0..511
            int kk = i >> 4;                  // 0..31
            int p4 = (i & 15) * 4;
            float4 v = *(const float4*)&Xb[(size_t)(k0 + kk) * HW + p0 + p4];
            int kg = kk >> 3, kl = kk & 7;
            float vv[4] = {v.x, v.y, v.z, v.w};
            #pragma unroll
            for (int jj = 0; jj < 4; ++jj) {
                int pos = p4 + jj;
                int kgs = kg ^ ((pos >> 2) & 3);
                Bs[pos * 40 + kgs * 8 + kl] = f2bf(vv[jj]);
            }
        }
        __syncthreads();

        short8 aF[2], bF[2];
        #pragma unroll
        for (int mi = 0; mi < 2; ++mi)
            aF[mi] = *(const short8*)&As[(wm * 32 + mi * 16 + lrow) * 40 + lkg * 8];
        #pragma unroll
        for (int ni = 0; ni < 2; ++ni) {
            int pos = wn * 32 + ni * 16 + lrow;
            int kgs = lkg ^ ((pos >> 2) & 3);
            bF[ni] = *(const short8*)&Bs[pos * 40 + kgs * 8];
        }
        #pragma unroll
        for (int mi = 0; mi < 2; ++mi)
            #pragma unroll
            for (int ni = 0; ni < 2; ++ni)
                acc[mi][ni] = __builtin_amdgcn_mfma_f32_16x16x32_bf16(
                    aF[mi], bF[ni], acc[mi][ni], 0, 0, 0);
    }

    // epilogue: D row = (lane>>4)*4 + reg, col = lane&15  [m89-verified]
    #pragma unroll
    for (int mi = 0; mi < 2; ++mi) {
        #pragma unroll
        for (int r = 0; r < 4; ++r) {
            int co = c0 + wm * 32 + mi * 16 + lkg * 4 + r;
            float s  = gg[co] * BN_RS;
            float bi = bb[co];
            #pragma unroll
            for (int ni = 0; ni < 2; ++ni) {
                int col = p0 + wn * 32 + ni * 16 + lrow;
                float v = acc[mi][ni][r];
                Y[((size_t)b * CO + co) * HW + col] = silu_f(fmaf(v, s, bi));
            }
        }
    }
}

// -------- 3x3 conv (256 -> 18), pad 1, channel-split partial sums --------
__global__ __launch_bounds__(256) void k_conv_off(
    const float* __restrict__ Hh, const float* __restrict__ Wo,
    float* __restrict__ OffP)
{
    const int y = blockIdx.x;
    const int b = blockIdx.y;
    const int q = blockIdx.z;
    const int tid = threadIdx.x;
    const int x = tid & 63;
    const int g = tid >> 6;

    __shared__ __align__(16) float hs[3][32][66];
    __shared__ __align__(16) float ws[18][32][12];

    if (tid < 96) {
        int r = tid >> 5, ci = tid & 31;
        hs[r][ci][0] = 0.f; hs[r][ci][65] = 0.f;
    }

    float acc[5] = {0.f, 0.f, 0.f, 0.f, 0.f};
    const float* Hb = Hh + (size_t)b * 256 * HW;

    for (int cc = 0; cc < 2; ++cc) {
        const int c0 = q * 64 + cc * 32;
        __syncthreads();
        for (int i = tid; i < 5184; i += 256) {
            int co = i / 288, r = i % 288;
            int ci = r / 9, t = r - ci * 9;
            ws[co][ci][t] = Wo[(size_t)co * 2304 + (size_t)(c0 + ci) * 9 + t];
        }
        #pragma unroll
        for (int it = 0; it < 6; ++it) {
            int i   = tid + it * 256;
            int r   = i >> 9;
            int rem = i & 511;
            int ci  = rem >> 4;
            int x4  = (rem & 15) << 2;
            int yy  = y + r - 1;
            float4 v = make_float4(0.f, 0.f, 0.f, 0.f);
            if ((unsigned)yy < 64u)
                v = *(const float4*)&Hb[(size_t)(c0 + ci) * HW + yy * 64 + x4];
            hs[r][ci][1 + x4] = v.x;
            hs[r][ci][2 + x4] = v.y;
            hs[r][ci][3 + x4] = v.z;
            hs[r][ci][4 + x4] = v.w;
        }
        __syncthreads();
        #pragma unroll 2
        for (int ci = 0; ci < 32; ++ci) {
            float v[9];
            #pragma unroll
            for (int r = 0; r < 3; ++r) {
                v[r * 3 + 0] = hs[r][ci][x];
                v[r * 3 + 1] = hs[r][ci][x + 1];
                v[r * 3 + 2] = hs[r][ci][x + 2];
            }
            #pragma unroll
            for (int j = 0; j < 5; ++j) {
                int co = g + (j << 2);
                if (co < 18) {
                    const float4 w0 = *(const float4*)&ws[co][ci][0];
                    const float4 w1 = *(const float4*)&ws[co][ci][4];
                    const float  w8 = ws[co][ci][8];
                    float a = acc[j];
                    a = fmaf(w0.x, v[0], a); a = fmaf(w0.y, v[1], a);
                    a = fmaf(w0.z, v[2], a); a = fmaf(w0.w, v[3], a);
                    a = fmaf(w1.x, v[4], a); a = fmaf(w1.y, v[5], a);
                    a = fmaf(w1.z, v[6], a); a = fmaf(w1.w, v[7], a);
                    a = fmaf(w8,   v[8], a);
                    acc[j] = a;
                }
            }
        }
    }
    #pragma unroll
    for (int j = 0; j < 5; ++j) {
        int co = g + (j << 2);
        if (co < 18)
            OffP[(((size_t)q * 4 + b) * 18 + co) * HW + y * 64 + x] = acc[j];
    }
}

// -------- combine 4 channel-split partials + bias -> final offsets --------
__global__ __launch_bounds__(256) void k_off_combine(
    const float* __restrict__ OffP, const float* __restrict__ Bo,
    float* __restrict__ Off)
{
    const int bt = blockIdx.x;         // b*18 + t, 72 blocks
    const int b = bt / 18, t = bt - b * 18;
    const float bias = Bo[t];
    const size_t plane = ((size_t)b * 18 + t) * HW;
    #pragma unroll
    for (int it = 0; it < 4; ++it) {
        int p4 = (threadIdx.x + it * 256) * 4;
        float4 s = *(const float4*)&OffP[plane + p4];
        #pragma unroll
        for (int q = 1; q < 4; ++q) {
            float4 v = *(const float4*)&OffP[((size_t)q * 4 * 18) * HW + plane + p4];
            s.x += v.x; s.y += v.y; s.z += v.z; s.w += v.w;
        }
        s.x += bias; s.y += bias; s.z += bias; s.w += bias;
        *(float4*)&Off[plane + p4] = s;
    }
}

// ------------- deformable depthwise 3x3 + BN + SiLU + residual -------------
// grid (y=64, b=4, q=8): each block does channels [q*32, q*32+32), 8 per thread.
__global__ __launch_bounds__(256) void k_deform(
    const float* __restrict__ Hh, const float* __restrict__ Off,
    const float* __restrict__ Wd, const float* __restrict__ Gb,
    const float* __restrict__ Bb, float* __restrict__ H2)
{
    const int y = blockIdx.x;
    const int b = blockIdx.y;
    const int q = blockIdx.z;
    const int tid = threadIdx.x;
    const int x = tid & 63;
    const int g = tid >> 6;
    const int pos = y * 64 + x;

    int   i00[9], i01[9], i10[9], i11[9];
    float w00[9], w01[9], w10[9], w11[9];

    const float* Ob = Off + (size_t)b * 18 * HW + pos;
    #pragma unroll
    for (int k = 0; k < 9; ++k) {
        float dy = Ob[(size_t)(2 * k) * HW];
        float dx = Ob[(size_t)(2 * k + 1) * HW];
        float py = (float)(y + k / 3 - 1) + dy;
        float px = (float)(x + k % 3 - 1) + dx;
        float fy0 = floorf(py), fx0 = floorf(px);
        int y0 = (int)fy0, x0 = (int)fx0;
        float fy = py - fy0, fx = px - fx0;
        int y1 = y0 + 1, x1 = x0 + 1;
        float gy0 = 1.0f - fy, gx0 = 1.0f - fx;
        bool vy0 = ((unsigned)y0 < 64u), vy1 = ((unsigned)y1 < 64u);
        bool vx0 = ((unsigned)x0 < 64u), vx1 = ((unsigned)x1 < 64u);
        int cy0 = clamp64(y0), cy1 = clamp64(y1);
        int cx0 = clamp64(x0), cx1 = clamp64(x1);
        i00[k] = cy0 * 64 + cx0; i01[k] = cy0 * 64 + cx1;
        i10[k] = cy1 * 64 + cx0; i11[k] = cy1 * 64 + cx1;
        w00[k] = (vy0 && vx0) ? gy0 * gx0 : 0.0f;
        w01[k] = (vy0 && vx1) ? gy0 * fx  : 0.0f;
        w10[k] = (vy1 && vx0) ? fy  * gx0 : 0.0f;
        w11[k] = (vy1 && vx1) ? fy  * fx  : 0.0f;
    }

    const int cbase = q * 32 + g * 8;
    #pragma unroll 2
    for (int j = 0; j < 8; ++j) {
        const int c = cbase + j;
        const float* hb = Hh + ((size_t)(b * 256 + c) << 12);
        const float* wd = Wd + c * 9;
        float acc = 0.0f;
        #pragma unroll
        for (int k = 0; k < 9; ++k) {
            float val = hb[i00[k]] * w00[k] + hb[i01[k]] * w01[k]
                      + hb[i10[k]] * w10[k] + hb[i11[k]] * w11[k];
            acc = fmaf(val, wd[k], acc);
        }
        float t = fmaf(acc, Gb[c] * BN_RS, Bb[c]);
        H2[((size_t)(b * 256 + c) << 12) + pos] = silu_f(t) + hb[pos];
    }
}

// ---------------- SE: global mean over HxW ----------------
__global__ __launch_bounds__(256) void k_se_reduce(
    const float* __restrict__ Y, float* __restrict__ sb)
{
    const int bc = blockIdx.x;
    const float4* p = (const float4*)(Y + (size_t)bc * HW);
    int tid = threadIdx.x;
    float s = 0.f;
    #pragma unroll
    for (int it = 0; it < 4; ++it) {
        float4 v = p[tid + it * 256];
        s += v.x + v.y + v.z + v.w;
    }
    #pragma unroll
    for (int o = 32; o > 0; o >>= 1) s += __shfl_down(s, o);
    __shared__ float red[4];
    if ((tid & 63) == 0) red[tid >> 6] = s;
    __syncthreads();
    if (tid == 0) sb[bc] = (red[0] + red[1] + red[2] + red[3]) * (1.0f / 4096.0f);
}

// ---------------- SE: fc1(silu) + fc2(sigmoid) ----------------
__global__ __launch_bounds__(256) void k_se_fc(
    const float* __restrict__ sb, const float* __restrict__ wf1,
    const float* __restrict__ bf1, const float* __restrict__ wf2,
    const float* __restrict__ bf2, float* __restrict__ s2)
{
    const int b = blockIdx.x;
    const int t = threadIdx.x;
    __shared__ float sv[512];
    __shared__ float s1[32];
    sv[t]       = sb[b * 512 + t];
    sv[t + 256] = sb[b * 512 + t + 256];
    __syncthreads();
    if (t < 32) {
        float a = bf1[t];
        const float* w = wf1 + t * 512;
        for (int i = 0; i < 512; ++i) a = fmaf(w[i], sv[i], a);
        s1[t] = silu_f(a);
    }
    __syncthreads();
    #pragma unroll
    for (int it = 0; it < 2; ++it) {
        int co = t + it * 256;
        float a = bf2[co];
        const float* w = wf2 + co * 32;
        #pragma unroll
        for (int i = 0; i < 32; ++i) a = fmaf(w[i], s1[i], a);
        s2[b * 512 + co] = 1.0f / (1.0f + __expf(-a));
    }
}

// ---------------- final: out *= s ----------------
__global__ __launch_bounds__(256) void k_se_scale(
    float* __restrict__ Y, const float* __restrict__ s2)
{
    size_t i = (size_t)blockIdx.x * 256 + threadIdx.x;
    int bc = (int)(i >> 10);
    float sc = s2[bc];
    float4 v = ((float4*)Y)[i];
    v.x *= sc; v.y *= sc; v.z *= sc; v.w *= sc;
    ((float4*)Y)[i] = v;
}

extern "C" void kernel_launch(void* const* d_in, const int* in_sizes, int n_in,
                              void* d_out, int out_size, void* d_ws, size_t ws_size,
                              hipStream_t stream)
{
    const float* x   = (const float*)d_in[0];
    const float* w1  = (const float*)d_in[1];
    const float* g1  = (const float*)d_in[2];
    const float* b1  = (const float*)d_in[3];
    const float* wof = (const float*)d_in[4];
    const float* bof = (const float*)d_in[5];
    const float* wdw = (const float*)d_in[6];
    const float* gb  = (const float*)d_in[7];
    const float* bbv = (const float*)d_in[8];
    const float* w2  = (const float*)d_in[9];
    const float* g2  = (const float*)d_in[10];
    const float* b2  = (const float*)d_in[11];
    const float* wf1 = (const float*)d_in[12];
    const float* bf1 = (const float*)d_in[13];
    const float* wf2 = (const float*)d_in[14];
    const float* bf2 = (const float*)d_in[15];
    float* out = (float*)d_out;

    const size_t n_h    = 4ull * 256 * HW;        // 4,194,304
    const size_t n_offp = 4ull * 4 * 18 * HW;     // 1,179,648
    const size_t n_off  = 4ull * 18 * HW;         //   294,912
    float* ws = (float*)d_ws;
    float *h, *offp, *offc, *h2, *sb, *s2;
    size_t need = (2 * n_h + n_offp + n_off + 4096) * sizeof(float);
    if (ws_size >= need) {
        h = ws; offp = h + n_h; offc = offp + n_offp; h2 = offc + n_off;
        sb = h2 + n_h; s2 = sb + 2048;
    } else {
        h = out;  // dead before conv2 writes out
        offp = ws; offc = offp + n_offp; h2 = offc + n_off;
        sb = h2 + n_h; s2 = sb + 2048;
    }

    k_conv1x1_mfma<256, 512><<<dim3(64, 4, 4), 256, 0, stream>>>(x, w1, g1, b1, h);
    k_conv_off<<<dim3(64, 4, 4), 256, 0, stream>>>(h, wof, offp);
    k_off_combine<<<72, 256, 0, stream>>>(offp, bof, offc);
    k_deform<<<dim3(64, 4, 8), 256, 0, stream>>>(h, offc, wdw, gb, bbv, h2);
    k_conv1x1_mfma<512, 256><<<dim3(64, 8, 4), 256, 0, stream>>>(h2, w2, g2, b2, out);
    k_se_reduce<<<2048, 256, 0, stream>>>(out, sb);
    k_se_fc<<<4, 256, 0, stream>>>(sb, wf1, bf1, wf2, bf2, s2);
    k_se_scale<<<8192, 256, 0, stream>>>(out, s2);
}